// Round 1
// baseline (78.342 us; speedup 1.0000x reference)
//
#include <hip/hip_runtime.h>
#include <math.h>

#define SEQ 16384
#define VOCAB 9
#define DIM 4

// ---------------------------------------------------------------------------
// Kernel 1: one block.
//   Phase A: 9-bin histogram of x via per-thread register counts +
//            wave shuffle-reduce (no atomics).
//   Phase B: threads 0..8 compute the 9x9 per-class output table:
//            g = emb@proj_w.T + proj_b  (9x4, only 9 distinct rows exist)
//            s_tc = <g_t, g_c>;  softmax row weights = count[c]*exp(s_tc - m)
//            attn-out = weighted avg of g rows; relu; forw; classifier; softmax.
// ---------------------------------------------------------------------------
__global__ __launch_bounds__(1024) void build_table_kernel(
    const int* __restrict__ x,
    const float* __restrict__ emb,
    const float* __restrict__ proj_w, const float* __restrict__ proj_b,
    const float* __restrict__ forw_w, const float* __restrict__ forw_b,
    const float* __restrict__ prj_w, const float* __restrict__ prj_b,
    float* __restrict__ table)   // d_ws: 81 floats
{
    const int tid = threadIdx.x;

    // ---- Phase A: histogram ----
    int local[VOCAB];
#pragma unroll
    for (int c = 0; c < VOCAB; ++c) local[c] = 0;

    for (int i = tid; i < SEQ; i += 1024) {
        const int t = x[i];
#pragma unroll
        for (int c = 0; c < VOCAB; ++c) local[c] += (t == c) ? 1 : 0;
    }

    // wave(64)-wide shuffle reduction
#pragma unroll
    for (int c = 0; c < VOCAB; ++c) {
#pragma unroll
        for (int off = 32; off > 0; off >>= 1)
            local[c] += __shfl_down(local[c], off);
    }

    __shared__ int whist[16][VOCAB];   // 1024/64 = 16 waves
    __shared__ int hist[VOCAB];
    __shared__ float g[VOCAB][DIM];

    const int wid  = tid >> 6;
    const int lane = tid & 63;
    if (lane == 0) {
#pragma unroll
        for (int c = 0; c < VOCAB; ++c) whist[wid][c] = local[c];
    }

    // g = emb @ proj_w.T + proj_b  (independent of histogram)
    if (tid < VOCAB) {
#pragma unroll
        for (int d = 0; d < DIM; ++d) {
            float acc = proj_b[d];
#pragma unroll
            for (int k = 0; k < DIM; ++k)
                acc += emb[tid * DIM + k] * proj_w[d * DIM + k];
            g[tid][d] = acc;
        }
    }
    __syncthreads();

    if (tid < VOCAB) {
        int s = 0;
#pragma unroll
        for (int w = 0; w < 16; ++w) s += whist[w][tid];
        hist[tid] = s;
    }
    __syncthreads();

    // ---- Phase B: per-class table row ----
    if (tid < VOCAB) {
        const int t = tid;

        float sc[VOCAB];
        float m = -INFINITY;
#pragma unroll
        for (int c = 0; c < VOCAB; ++c) {
            float s = 0.f;
#pragma unroll
            for (int d = 0; d < DIM; ++d) s += g[t][d] * g[c][d];
            sc[c] = s;
            if (hist[c] > 0 && s > m) m = s;
        }

        float Z = 0.f;
        float o[DIM] = {0.f, 0.f, 0.f, 0.f};
#pragma unroll
        for (int c = 0; c < VOCAB; ++c) {
            const float w = (float)hist[c] * __expf(sc[c] - m) ;
            // use precise expf for closeness to numpy:
            const float wp = (float)hist[c] * expf(sc[c] - m);
            (void)w;
            Z += wp;
#pragma unroll
            for (int d = 0; d < DIM; ++d) o[d] += wp * g[c][d];
        }
        const float invZ = 1.f / Z;

        float r[DIM];
#pragma unroll
        for (int d = 0; d < DIM; ++d) {
            const float v = o[d] * invZ;
            r[d] = v > 0.f ? v : 0.f;           // relu(attn @ h)
        }

        float f[DIM];
#pragma unroll
        for (int d = 0; d < DIM; ++d) {
            float acc = forw_b[d];
#pragma unroll
            for (int k = 0; k < DIM; ++k) acc += r[k] * forw_w[d * DIM + k];
            f[d] = acc;
        }

        float lg[VOCAB];
        float lm = -INFINITY;
#pragma unroll
        for (int v = 0; v < VOCAB; ++v) {
            float acc = prj_b[v];
#pragma unroll
            for (int k = 0; k < DIM; ++k) acc += f[k] * prj_w[v * DIM + k];
            lg[v] = acc;
            lm = fmaxf(lm, acc);
        }
        float lz = 0.f;
#pragma unroll
        for (int v = 0; v < VOCAB; ++v) { lg[v] = expf(lg[v] - lm); lz += lg[v]; }
        const float linv = 1.f / lz;
#pragma unroll
        for (int v = 0; v < VOCAB; ++v) table[t * VOCAB + v] = lg[v] * linv;
    }
}

// ---------------------------------------------------------------------------
// Kernel 2: gather — out[i, :] = table[x[i], :], fully coalesced writes.
// 147456 elements = 576 blocks * 256 threads exactly.
// ---------------------------------------------------------------------------
__global__ __launch_bounds__(256) void gather_kernel(
    const int* __restrict__ x,
    const float* __restrict__ table,
    float* __restrict__ out)
{
    __shared__ float tl[VOCAB * VOCAB];
    if (threadIdx.x < VOCAB * VOCAB) tl[threadIdx.x] = table[threadIdx.x];
    __syncthreads();

    const int idx = blockIdx.x * 256 + threadIdx.x;   // < 147456
    const int i = idx / 9;                            // magic-mul division
    const int k = idx - i * 9;
    const int t = x[i];
    out[idx] = tl[t * VOCAB + k];
}

extern "C" void kernel_launch(void* const* d_in, const int* in_sizes, int n_in,
                              void* d_out, int out_size, void* d_ws, size_t ws_size,
                              hipStream_t stream) {
    const int*   x      = (const int*)d_in[0];
    const float* emb    = (const float*)d_in[1];
    const float* proj_w = (const float*)d_in[2];
    const float* proj_b = (const float*)d_in[3];
    const float* forw_w = (const float*)d_in[4];
    const float* forw_b = (const float*)d_in[5];
    const float* prj_w  = (const float*)d_in[6];
    const float* prj_b  = (const float*)d_in[7];

    float* table = (float*)d_ws;          // 81 floats of scratch
    float* out   = (float*)d_out;         // 16384 * 9 floats

    build_table_kernel<<<1, 1024, 0, stream>>>(
        x, emb, proj_w, proj_b, forw_w, forw_b, prj_w, prj_b, table);

    gather_kernel<<<(SEQ * VOCAB) / 256, 256, 0, stream>>>(x, table, out);
}

// Round 2
// 76.182 us; speedup vs baseline: 1.0283x; 1.0283x over previous
//
#include <hip/hip_runtime.h>
#include <math.h>

#define SEQ 16384
#define VOCAB 9
#define DIM 4
#define NBLK 144          // 144 * 1024 = 147456 = SEQ*VOCAB output elements
#define NTHR 1024

// ---------------------------------------------------------------------------
// Single fused kernel. Key insight: x has only VOCAB=9 distinct values, and
// every op in the reference is row-wise, so the entire (S,VOCAB) output is a
// lookup out[i,:] = table[x[i],:] where table is 9x9 and depends on x only
// through its 9-bin histogram.
//
// Each block independently:
//   1. computes the histogram of all of x (register counts + wave64 shuffle
//      reduce + LDS combine) -- x is 64 KB, L2-resident after first touch;
//   2. threads 0..8 compute the 9x9 table entirely in LDS:
//        g = emb @ proj_w.T + proj_b                       (9x4)
//        s_tc = <g_t, g_c>;  w_c = hist[c] * exp(s_tc - m)
//        o = (sum_c w_c g_c) / Z;  relu; forw; classifier; softmax
//   3. each thread writes exactly one output element (coalesced).
// No workspace, no second launch, no inter-kernel dependency.
// ---------------------------------------------------------------------------
__global__ __launch_bounds__(NTHR) void bert_fused_kernel(
    const int* __restrict__ x,
    const float* __restrict__ emb,
    const float* __restrict__ proj_w, const float* __restrict__ proj_b,
    const float* __restrict__ forw_w, const float* __restrict__ forw_b,
    const float* __restrict__ prj_w, const float* __restrict__ prj_b,
    float* __restrict__ out)
{
    const int tid = threadIdx.x;

    __shared__ int   whist[NTHR / 64][VOCAB];
    __shared__ int   hist[VOCAB];
    __shared__ float g[VOCAB][DIM];
    __shared__ float tl[VOCAB * VOCAB];

    // ---- 1. histogram of x (full sequence, per block) ----
    int local[VOCAB];
#pragma unroll
    for (int c = 0; c < VOCAB; ++c) local[c] = 0;

#pragma unroll
    for (int i = tid; i < SEQ; i += NTHR) {
        const int t = x[i];
#pragma unroll
        for (int c = 0; c < VOCAB; ++c) local[c] += (t == c) ? 1 : 0;
    }

#pragma unroll
    for (int c = 0; c < VOCAB; ++c) {
#pragma unroll
        for (int off = 32; off > 0; off >>= 1)
            local[c] += __shfl_down(local[c], off);
    }

    const int wid  = tid >> 6;
    const int lane = tid & 63;
    if (lane == 0) {
#pragma unroll
        for (int c = 0; c < VOCAB; ++c) whist[wid][c] = local[c];
    }

    // g = emb @ proj_w.T + proj_b (independent of histogram, overlap it)
    if (tid < VOCAB) {
#pragma unroll
        for (int d = 0; d < DIM; ++d) {
            float acc = proj_b[d];
#pragma unroll
            for (int k = 0; k < DIM; ++k)
                acc += emb[tid * DIM + k] * proj_w[d * DIM + k];
            g[tid][d] = acc;
        }
    }
    __syncthreads();

    if (tid < VOCAB) {
        int s = 0;
#pragma unroll
        for (int w = 0; w < NTHR / 64; ++w) s += whist[w][tid];
        hist[tid] = s;
    }
    __syncthreads();

    // ---- 2. 9x9 table (threads 0..8, one class-row each) ----
    if (tid < VOCAB) {
        const int t = tid;

        float sc[VOCAB];
        float m = -INFINITY;
#pragma unroll
        for (int c = 0; c < VOCAB; ++c) {
            float s = 0.f;
#pragma unroll
            for (int d = 0; d < DIM; ++d) s += g[t][d] * g[c][d];
            sc[c] = s;
            if (hist[c] > 0 && s > m) m = s;   // max over classes present in x
        }

        float Z = 0.f;
        float o[DIM] = {0.f, 0.f, 0.f, 0.f};
#pragma unroll
        for (int c = 0; c < VOCAB; ++c) {
            const float w = (float)hist[c] * expf(sc[c] - m);
            Z += w;
#pragma unroll
            for (int d = 0; d < DIM; ++d) o[d] += w * g[c][d];
        }
        const float invZ = 1.f / Z;

        float r[DIM];
#pragma unroll
        for (int d = 0; d < DIM; ++d) {
            const float v = o[d] * invZ;
            r[d] = v > 0.f ? v : 0.f;          // relu(attn @ h)
        }

        float f[DIM];
#pragma unroll
        for (int d = 0; d < DIM; ++d) {
            float acc = forw_b[d];
#pragma unroll
            for (int k = 0; k < DIM; ++k) acc += r[k] * forw_w[d * DIM + k];
            f[d] = acc;
        }

        float lg[VOCAB];
        float lm = -INFINITY;
#pragma unroll
        for (int v = 0; v < VOCAB; ++v) {
            float acc = prj_b[v];
#pragma unroll
            for (int k = 0; k < DIM; ++k) acc += f[k] * prj_w[v * DIM + k];
            lg[v] = acc;
            lm = fmaxf(lm, acc);
        }
        float lz = 0.f;
#pragma unroll
        for (int v = 0; v < VOCAB; ++v) { lg[v] = expf(lg[v] - lm); lz += lg[v]; }
        const float linv = 1.f / lz;
#pragma unroll
        for (int v = 0; v < VOCAB; ++v) tl[t * VOCAB + v] = lg[v] * linv;
    }
    __syncthreads();

    // ---- 3. gather: one output element per thread, coalesced store ----
    const int idx = blockIdx.x * NTHR + tid;   // < 147456
    const int i = idx / VOCAB;                 // magic-mul division
    const int k = idx - i * VOCAB;
    const int t = x[i];                        // L2 hit (x read in phase 1)
    out[idx] = tl[t * VOCAB + k];
}

extern "C" void kernel_launch(void* const* d_in, const int* in_sizes, int n_in,
                              void* d_out, int out_size, void* d_ws, size_t ws_size,
                              hipStream_t stream) {
    const int*   x      = (const int*)d_in[0];
    const float* emb    = (const float*)d_in[1];
    const float* proj_w = (const float*)d_in[2];
    const float* proj_b = (const float*)d_in[3];
    const float* forw_w = (const float*)d_in[4];
    const float* forw_b = (const float*)d_in[5];
    const float* prj_w  = (const float*)d_in[6];
    const float* prj_b  = (const float*)d_in[7];

    bert_fused_kernel<<<NBLK, NTHR, 0, stream>>>(
        x, emb, proj_w, proj_b, forw_w, forw_b, prj_w, prj_b, (float*)d_out);
}